// Round 1
// baseline (325.316 us; speedup 1.0000x reference)
//
#include <hip/hip_runtime.h>
#include <math.h>

#define NT 512
#define EDGES 2048
#define SROW 129
#define SENT 0xFFFF

// ---------------- per-subgraph fused pipeline ----------------
struct SmemA {
  float xbuf[256 * SROW];          // node features / h / W staging (132096 B)
  unsigned short rowc[EDGES];      // current row index (SENT = dropped)
  unsigned short colc[EDGES];
  float ewl[EDGES];                // original edge weights
  float degs[256];
  float diss[256];
  int   csr_off[257];
  int   csr_cnt[256];
  unsigned short csr_ids[EDGES];
  float hsv[256];                  // score-gcn h
  float scorev[256];
  short newid[256];
  short perm[256];
  float vals[256];
};

template<int NN, int K, int NPT, int FPT>
__device__ __forceinline__ void run_stage(
    SmemA& sm,
    const float* __restrict__ xg,        // global x (stage 1) or nullptr (x in sm.xbuf)
    const float* __restrict__ W,         // 128x128
    const float* __restrict__ b,         // 128
    const float* __restrict__ Wp,        // 128
    const float* __restrict__ bp,        // 1
    float* __restrict__ leaf_out,        // 256 floats: [max(128), mean(128)]
    bool do_remap)
{
  constexpr int FG = 128 / FPT;
  constexpr int NG = NN / NPT;
  static_assert(NG * FG == NT, "thread decomposition mismatch");
  const int tid = threadIdx.x;

  // ---- build graph: deg, dis, CSR (by destination col) ----
  if (tid < NN) { sm.degs[tid] = 1.0f; sm.csr_cnt[tid] = 0; }
  __syncthreads();
  for (int e = tid; e < EDGES; e += NT) {
    if (sm.rowc[e] != SENT) {
      atomicAdd(&sm.degs[sm.colc[e]], sm.ewl[e]);
      atomicAdd(&sm.csr_cnt[sm.colc[e]], 1);
    }
  }
  __syncthreads();
  if (tid < NN) sm.diss[tid] = rsqrtf(sm.degs[tid]);
  if (tid < NN) sm.csr_off[tid + 1] = sm.csr_cnt[tid];
  if (tid == 0) sm.csr_off[0] = 0;
  __syncthreads();
  for (int s = 1; s < NN; s <<= 1) {           // Hillis-Steele inclusive scan
    int t = 0;
    if (tid < NN && tid >= s) t = sm.csr_off[tid + 1 - s];
    __syncthreads();
    if (tid < NN && tid >= s) sm.csr_off[tid + 1] += t;
    __syncthreads();
  }
  if (tid < NN) sm.csr_cnt[tid] = 0;
  __syncthreads();
  for (int e = tid; e < EDGES; e += NT) {
    if (sm.rowc[e] != SENT) {
      int v = sm.colc[e];
      int p = atomicAdd(&sm.csr_cnt[v], 1);
      sm.csr_ids[sm.csr_off[v] + p] = (unsigned short)e;
    }
  }
  __syncthreads();

  // ---- stage W into LDS (region above current x rows; stage1 uses offset 0) ----
  float* Wl = (NN == 256) ? sm.xbuf : (sm.xbuf + NN * SROW);
  for (int i = tid; i < 128 * 128; i += NT) Wl[i] = W[i];
  __syncthreads();

  // ---- matmul: h = x @ W (register-blocked NPT nodes x FPT feats) ----
  const int fg = tid % FG, ng = tid / FG;
  const int fbase = fg * FPT;
  const int vbase = ng * NPT;
  float acc[NPT][FPT];
#pragma unroll
  for (int i = 0; i < NPT; i++)
#pragma unroll
    for (int j = 0; j < FPT; j++) acc[i][j] = 0.0f;

  for (int k4 = 0; k4 < 128; k4 += 4) {
    float xv[NPT][4];
    if (xg != nullptr) {
#pragma unroll
      for (int i = 0; i < NPT; i++) {
        const float4 t = *reinterpret_cast<const float4*>(xg + (vbase + i) * 128 + k4);
        xv[i][0] = t.x; xv[i][1] = t.y; xv[i][2] = t.z; xv[i][3] = t.w;
      }
    } else {
#pragma unroll
      for (int i = 0; i < NPT; i++)
#pragma unroll
        for (int kk = 0; kk < 4; kk++)
          xv[i][kk] = sm.xbuf[(vbase + i) * SROW + k4 + kk];
    }
#pragma unroll
    for (int kk = 0; kk < 4; kk++) {
#pragma unroll
      for (int j = 0; j < FPT; j++) {
        float w = Wl[(k4 + kk) * 128 + fbase + j];
#pragma unroll
        for (int i = 0; i < NPT; i++) acc[i][j] += xv[i][kk] * w;
      }
    }
  }
  __syncthreads();          // all x/W reads complete before overwrite
#pragma unroll
  for (int i = 0; i < NPT; i++)
#pragma unroll
    for (int j = 0; j < FPT; j++)
      sm.xbuf[(vbase + i) * SROW + fbase + j] = acc[i][j];
  __syncthreads();

  // ---- aggregation: agg[v] = sum_{e: col=v} dis[row]*ew*dis[v] * h[row] ----
  float agg[NPT][FPT];
#pragma unroll
  for (int i = 0; i < NPT; i++)
#pragma unroll
    for (int j = 0; j < FPT; j++) agg[i][j] = 0.0f;
#pragma unroll
  for (int i = 0; i < NPT; i++) {
    const int v = vbase + i;
    const int beg = sm.csr_off[v], end = sm.csr_off[v + 1];
    const float dv = sm.diss[v];
    for (int e2 = beg; e2 < end; e2++) {
      const int e = sm.csr_ids[e2];
      const int r = sm.rowc[e];
      const float nrm = sm.diss[r] * sm.ewl[e] * dv;
#pragma unroll
      for (int j = 0; j < FPT; j++)
        agg[i][j] += nrm * sm.xbuf[r * SROW + fbase + j];
    }
  }
  __syncthreads();          // all aggregation reads done before in-place out
#pragma unroll
  for (int i = 0; i < NPT; i++) {
    const int v = vbase + i;
    const float invd = 1.0f / sm.degs[v];
#pragma unroll
    for (int j = 0; j < FPT; j++) {
      const float h = sm.xbuf[v * SROW + fbase + j];
      const float o = agg[i][j] + h * invd + b[fbase + j];
      sm.xbuf[v * SROW + fbase + j] = fmaxf(o, 0.0f);   // ReLU (main gcn always relu'd)
    }
  }
  __syncthreads();

  // ---- score gcn: hs = x1 @ Wp ; score = agg(hs) + hs/deg + bp ----
  if (tid < NN) sm.hsv[tid] = 0.0f;
  __syncthreads();
#pragma unroll
  for (int i = 0; i < NPT; i++) {
    float part = 0.0f;
#pragma unroll
    for (int j = 0; j < FPT; j++)
      part += sm.xbuf[(vbase + i) * SROW + fbase + j] * Wp[fbase + j];
    atomicAdd(&sm.hsv[vbase + i], part);
  }
  __syncthreads();
  if (tid < NN) {
    const int v = tid;
    const int beg = sm.csr_off[v], end = sm.csr_off[v + 1];
    const float dv = sm.diss[v];
    float s = 0.0f;
    for (int e2 = beg; e2 < end; e2++) {
      const int e = sm.csr_ids[e2];
      const int r = sm.rowc[e];
      s += sm.diss[r] * sm.ewl[e] * dv * sm.hsv[r];
    }
    sm.scorev[v] = s + sm.hsv[v] / sm.degs[v] + bp[0];
  }
  __syncthreads();

  // ---- exact top-k ranking (desc, ties -> lower index) ----
  if (tid < NN) {
    const float sv = sm.scorev[tid];
    int rank = 0;
    for (int u = 0; u < NN; u++) {
      const float su = sm.scorev[u];
      rank += (su > sv) || (su == sv && u < tid);
    }
    if (rank < K) { sm.perm[rank] = (short)tid; sm.vals[rank] = sv; sm.newid[tid] = (short)rank; }
    else sm.newid[tid] = -1;
  }
  __syncthreads();

  // ---- pool: x_new[i] = x[perm[i]] * tanh(vals[i]) (in-place via registers) ----
  {
    constexpr int TPR = NT / K;
    constexpr int FP2 = 128 / TPR;
    const int i = tid / TPR;
    const int fb2 = (tid % TPR) * FP2;
    const int src = sm.perm[i];
    const float g = tanhf(sm.vals[i]);
    float tmp[FP2];
#pragma unroll
    for (int j = 0; j < FP2; j++) tmp[j] = sm.xbuf[src * SROW + fb2 + j];
    __syncthreads();
#pragma unroll
    for (int j = 0; j < FP2; j++) sm.xbuf[i * SROW + fb2 + j] = tmp[j] * g;
  }
  __syncthreads();

  // ---- readout: concat(max over K rows, mean over K rows) ----
  if (tid < 128) {
    float mx = -INFINITY, smv = 0.0f;
    for (int i = 0; i < K; i++) {
      const float v = sm.xbuf[i * SROW + tid];
      mx = fmaxf(mx, v); smv += v;
    }
    leaf_out[tid] = mx;
    leaf_out[128 + tid] = smv * (1.0f / K);
  }
  __syncthreads();

  // ---- remap edges into pooled id space ----
  if (do_remap) {
    for (int e = tid; e < EDGES; e += NT) {
      if (sm.rowc[e] != SENT) {
        const short r  = sm.newid[sm.rowc[e]];
        const short cc = sm.newid[sm.colc[e]];
        if (r < 0 || cc < 0) sm.rowc[e] = SENT;
        else { sm.rowc[e] = (unsigned short)r; sm.colc[e] = (unsigned short)cc; }
      }
    }
    __syncthreads();
  }
}

__global__ __launch_bounds__(NT)
void stageA_kernel(const float* __restrict__ x0,
                   const int* __restrict__ ei, const float* __restrict__ ew,
                   const float* __restrict__ W1, const float* __restrict__ b1,
                   const float* __restrict__ Wp1, const float* __restrict__ bp1,
                   const float* __restrict__ W2, const float* __restrict__ b2,
                   const float* __restrict__ Wp2, const float* __restrict__ bp2,
                   const float* __restrict__ W3, const float* __restrict__ b3,
                   const float* __restrict__ Wp3, const float* __restrict__ bp3,
                   float* __restrict__ gfeat)
{
  __shared__ SmemA sm;
  const int c = blockIdx.x;
  const int tid = threadIdx.x;
  const int* eic = ei + (size_t)c * 2 * EDGES;
  const float* ewc = ew + (size_t)c * EDGES;
  for (int e = tid; e < EDGES; e += NT) {
    sm.rowc[e] = (unsigned short)eic[e];
    sm.colc[e] = (unsigned short)eic[EDGES + e];
    sm.ewl[e]  = ewc[e];
  }
  __syncthreads();
  const float* xg = x0 + (size_t)c * 256 * 128;
  float* leaf = gfeat + (size_t)c * 768;
  run_stage<256, 128, 8, 8>(sm, xg,      W1, b1, Wp1, bp1, leaf + 0,   true);
  run_stage<128,  64, 4, 8>(sm, nullptr, W2, b2, Wp2, bp2, leaf + 256, true);
  run_stage< 64,  32, 4, 4>(sm, nullptr, W3, b3, Wp3, bp3, leaf + 512, false);
}

// ---------------- global stage ----------------
__global__ void parent_k(float* __restrict__ gfeat) {
  const int f = threadIdx.x;            // 768 threads
  float rsum = 0.0f;
  for (int p = 0; p < 16; p++) {
    float s = 0.0f;
    for (int b = 0; b < 16; b++) s += gfeat[(size_t)(p * 16 + b) * 768 + f];
    s *= (1.0f / 16.0f);
    gfeat[(size_t)(256 + p) * 768 + f] = s;
    rsum += s;
  }
  gfeat[(size_t)272 * 768 + f] = rsum * (1.0f / 16.0f);
}

__global__ void gmm_k(const float* __restrict__ gfeat, const float* __restrict__ Wg,
                      float* __restrict__ hG) {
  const int v = blockIdx.x, f = threadIdx.x;   // 273 x 256
  float a = 0.0f;
  for (int k = 0; k < 768; k++) a += gfeat[(size_t)v * 768 + k] * Wg[(size_t)k * 256 + f];
  hG[(size_t)v * 256 + f] = a;
}

__global__ void gdeg_k(const int* __restrict__ gei, float* __restrict__ degG) {
  __shared__ int cnt[273];
  const int tid = threadIdx.x;                 // 512 threads
  if (tid < 273) cnt[tid] = 0;
  __syncthreads();
  for (int e = tid; e < 8192; e += 512) atomicAdd(&cnt[gei[8192 + e]], 1);
  __syncthreads();
  if (tid < 273) degG[tid] = 1.0f + (float)cnt[tid];
}

__global__ void gagg_k(const float* __restrict__ hG, const float* __restrict__ degG,
                       const int* __restrict__ gei, const float* __restrict__ bg,
                       float* __restrict__ gx, float* __restrict__ out_ce) {
  __shared__ int lrows[8192];
  __shared__ int lcnt;
  const int v = blockIdx.x, tid = threadIdx.x; // 273 x 256
  if (tid == 0) lcnt = 0;
  __syncthreads();
  for (int e = tid; e < 8192; e += 256) {
    if (gei[8192 + e] == v) { int p = atomicAdd(&lcnt, 1); lrows[p] = gei[e]; }
  }
  __syncthreads();
  const float dv = rsqrtf(degG[v]);
  const int n = lcnt;
  float a = 0.0f;
  for (int i = 0; i < n; i++) {
    const int r = lrows[i];
    a += rsqrtf(degG[r]) * hG[(size_t)r * 256 + tid];
  }
  float val = a * dv + hG[(size_t)v * 256 + tid] / degG[v] + bg[tid];
  val = fmaxf(val, 0.0f);
  gx[(size_t)v * 256 + tid] = val;
  if (v < 256) out_ce[(size_t)v * 256 + tid] = val;
}

__global__ void emb_k(const float* __restrict__ gx,
                      const float* __restrict__ Wl1, const float* __restrict__ bl1,
                      const float* __restrict__ Wl2, const float* __restrict__ bl2,
                      float* __restrict__ A, float* __restrict__ B) {
  const int v = blockIdx.x, f = threadIdx.x;   // 273 x 256
  float a = bl1[f], b = bl2[f];
  for (int k = 0; k < 256; k++) {
    const float gv = gx[(size_t)v * 256 + k];
    a += gv * Wl1[(size_t)k * 256 + f];
    b += gv * Wl2[(size_t)k * 256 + f];
  }
  A[(size_t)v * 256 + f] = a;
  B[(size_t)v * 256 + f] = b;
}

__global__ void loss_k(const float* __restrict__ A, const float* __restrict__ B,
                       const int* __restrict__ gei, const int* __restrict__ nei,
                       float* __restrict__ acc) {
  const int gw = (blockIdx.x * blockDim.x + threadIdx.x) >> 6;  // 256 waves total
  const int lane = threadIdx.x & 63;
  float lsum = 0.0f;
  for (int idx = gw; idx < 16384; idx += 256) {
    const bool ispos = idx < 8192;
    const int e = ispos ? idx : idx - 8192;
    const int* ia = ispos ? gei : nei;
    const int s = ia[e], t = ia[8192 + e];
    float p = 0.0f;
#pragma unroll
    for (int j = 0; j < 4; j++)
      p += A[(size_t)s * 256 + lane + 64 * j] * B[(size_t)t * 256 + lane + 64 * j];
#pragma unroll
    for (int off = 32; off; off >>= 1) p += __shfl_xor(p, off, 64);
    const float z = ispos ? -p : p;
    lsum += fmaxf(z, 0.0f) + log1pf(expf(-fabsf(z)));
  }
  if (lane == 0) atomicAdd(acc, lsum);
}

__global__ void fin_k(const float* __restrict__ acc, float* __restrict__ out) {
  out[65536] = acc[0] * (1.0f / 8192.0f);
}

extern "C" void kernel_launch(void* const* d_in, const int* in_sizes, int n_in,
                              void* d_out, int out_size, void* d_ws, size_t ws_size,
                              hipStream_t stream) {
  const float* x   = (const float*)d_in[0];
  const int*   ei  = (const int*)d_in[1];
  const float* ew  = (const float*)d_in[2];
  const int*   gei = (const int*)d_in[3];
  const int*   nei = (const int*)d_in[4];
  const float* W1  = (const float*)d_in[5];
  const float* b1  = (const float*)d_in[6];
  const float* Wp1 = (const float*)d_in[7];
  const float* bp1 = (const float*)d_in[8];
  const float* W2  = (const float*)d_in[9];
  const float* b2  = (const float*)d_in[10];
  const float* Wp2 = (const float*)d_in[11];
  const float* bp2 = (const float*)d_in[12];
  const float* W3  = (const float*)d_in[13];
  const float* b3  = (const float*)d_in[14];
  const float* Wp3 = (const float*)d_in[15];
  const float* bp3 = (const float*)d_in[16];
  const float* Wg  = (const float*)d_in[17];
  const float* bg  = (const float*)d_in[18];
  const float* Wl1 = (const float*)d_in[19];
  const float* bl1 = (const float*)d_in[20];
  const float* Wl2 = (const float*)d_in[21];
  const float* bl2 = (const float*)d_in[22];

  float* ws    = (float*)d_ws;
  float* gfeat = ws;                          // 273*768
  float* hG    = gfeat + 273 * 768;           // 273*256
  float* degG  = hG + 273 * 256;              // 288 (padded)
  float* gx    = degG + 288;                  // 273*256
  float* Aemb  = gx + 273 * 256;              // 273*256
  float* Bemb  = Aemb + 273 * 256;            // 273*256
  float* lacc  = Bemb + 273 * 256;            // 1
  float* out   = (float*)d_out;

  hipMemsetAsync(lacc, 0, sizeof(float), stream);
  stageA_kernel<<<256, NT, 0, stream>>>(x, ei, ew, W1, b1, Wp1, bp1,
                                        W2, b2, Wp2, bp2, W3, b3, Wp3, bp3, gfeat);
  parent_k<<<1, 768, 0, stream>>>(gfeat);
  gmm_k<<<273, 256, 0, stream>>>(gfeat, Wg, hG);
  gdeg_k<<<1, 512, 0, stream>>>(gei, degG);
  gagg_k<<<273, 256, 0, stream>>>(hG, degG, gei, bg, gx, out);
  emb_k<<<273, 256, 0, stream>>>(gx, Wl1, bl1, Wl2, bl2, Aemb, Bemb);
  loss_k<<<64, 256, 0, stream>>>(Aemb, Bemb, gei, nei, lacc);
  fin_k<<<1, 1, 0, stream>>>(lacc, out);
}

// Round 2
// 296.145 us; speedup vs baseline: 1.0985x; 1.0985x over previous
//
#include <hip/hip_runtime.h>
#include <math.h>

#define NT 1024
#define EDGES 2048
#define SENT 0xFFFF

// ---------------- per-subgraph fused pipeline ----------------
// LDS budget: 131072 (xbuf) + ~28.7KB misc = ~159.7 KB < 160 KiB.
struct SmemA {
  float xbuf[256 * 128];           // swizzled node features (128 KB)
  unsigned short rowc[EDGES];      // current row index (SENT = dropped)
  unsigned short colc[EDGES];
  float ewl[EDGES];                // original edge weights
  float degs[256];
  float diss[256];
  int   csr_off[257];
  int   csr_cnt[256];
  unsigned short csr_ids[EDGES];
  float hsv[256];                  // score-gcn h
  float scorev[256];
  short newid[256];
  short perm[256];
  float vals[256];
};

// xbuf layout: row-major 128 floats/row, float4 chunks XOR-swizzled by row&7
// -> b128 accesses with lanes on distinct rows are bank-conflict-free.
__device__ __forceinline__ float4* xvec(float* xb, int row, int c4) {
  return reinterpret_cast<float4*>(xb + (row << 7) + ((c4 ^ (row & 7)) << 2));
}
__device__ __forceinline__ int xidx(int row, int col) {
  return (row << 7) + ((((col >> 2) ^ (row & 7)) << 2) | (col & 3));
}

template<int NN, int K, bool GX>
__device__ __forceinline__ void run_stage(
    SmemA& sm,
    const float* __restrict__ xg,        // global x (stage 1) else nullptr
    const float* __restrict__ W,         // 128x128 row-major [k][f]
    const float* __restrict__ b,         // 128
    const float* __restrict__ Wp,        // 128
    const float* __restrict__ bp,        // 1
    float* __restrict__ leaf_out,        // 256 floats: [max(128), mean(128)]
    bool do_remap)
{
  constexpr int NPT = NN / 64;           // nodes per lane (4/2/1)
  const int tid  = threadIdx.x;
  const int lane = tid & 63;
  // wave-uniform feature slice: wave w owns cols [8w, 8w+8)
  const int fbase = __builtin_amdgcn_readfirstlane((tid >> 6) << 3);
  const int c4b   = fbase >> 2;

  // ---- build graph: deg, dis, CSR (by destination col) ----
  if (tid < NN) { sm.degs[tid] = 1.0f; sm.csr_cnt[tid] = 0; }
  __syncthreads();
  for (int e = tid; e < EDGES; e += NT) {
    if (sm.rowc[e] != SENT) {
      atomicAdd(&sm.degs[sm.colc[e]], sm.ewl[e]);
      atomicAdd(&sm.csr_cnt[sm.colc[e]], 1);
    }
  }
  __syncthreads();
  if (tid < NN) {
    sm.diss[tid] = rsqrtf(sm.degs[tid]);
    sm.csr_off[tid + 1] = sm.csr_cnt[tid];
  }
  if (tid == 0) sm.csr_off[0] = 0;
  __syncthreads();
  for (int s = 1; s < NN; s <<= 1) {           // Hillis-Steele inclusive scan
    int t = 0;
    if (tid < NN && tid >= s) t = sm.csr_off[tid + 1 - s];
    __syncthreads();
    if (tid < NN && tid >= s) sm.csr_off[tid + 1] += t;
    __syncthreads();
  }
  if (tid < NN) sm.csr_cnt[tid] = 0;
  __syncthreads();
  for (int e = tid; e < EDGES; e += NT) {
    if (sm.rowc[e] != SENT) {
      int v = sm.colc[e];
      int p = atomicAdd(&sm.csr_cnt[v], 1);
      sm.csr_ids[sm.csr_off[v] + p] = (unsigned short)e;
    }
  }
  __syncthreads();

  // ---- matmul: h = x @ W. Lane owns rows lane+64i; wave owns 8 cols.
  // W reads are wave-uniform -> scalar (constant-cache) loads, no LDS.
  float acc[NPT][8];
#pragma unroll
  for (int i = 0; i < NPT; i++)
#pragma unroll
    for (int j = 0; j < 8; j++) acc[i][j] = 0.0f;

  for (int k4 = 0; k4 < 128; k4 += 4) {
    float xv[NPT][4];
#pragma unroll
    for (int i = 0; i < NPT; i++) {
      float4 t;
      if (GX) t = *reinterpret_cast<const float4*>(xg + ((lane + (i << 6)) << 7) + k4);
      else    t = *xvec(sm.xbuf, lane + (i << 6), k4 >> 2);
      xv[i][0] = t.x; xv[i][1] = t.y; xv[i][2] = t.z; xv[i][3] = t.w;
    }
#pragma unroll
    for (int kk = 0; kk < 4; kk++) {
      const float* wr = W + ((k4 + kk) << 7) + fbase;
      const float4 wa = *reinterpret_cast<const float4*>(wr);
      const float4 wb = *reinterpret_cast<const float4*>(wr + 4);
      const float wv[8] = {wa.x, wa.y, wa.z, wa.w, wb.x, wb.y, wb.z, wb.w};
#pragma unroll
      for (int i = 0; i < NPT; i++)
#pragma unroll
        for (int j = 0; j < 8; j++)
          acc[i][j] = fmaf(xv[i][kk], wv[j], acc[i][j]);
    }
  }
  __syncthreads();                 // stages 2/3: x reads done before overwrite

  // ---- write h to xbuf (conflict-free swizzled b128 writes) ----
#pragma unroll
  for (int i = 0; i < NPT; i++) {
    const int v = lane + (i << 6);
    *xvec(sm.xbuf, v, c4b)     = make_float4(acc[i][0], acc[i][1], acc[i][2], acc[i][3]);
    *xvec(sm.xbuf, v, c4b + 1) = make_float4(acc[i][4], acc[i][5], acc[i][6], acc[i][7]);
  }
  __syncthreads();

  // ---- aggregation: agg[v] = sum_{e: col=v} dis[row]*ew*dis[v] * h[row] ----
  float agg[NPT][8];
#pragma unroll
  for (int i = 0; i < NPT; i++)
#pragma unroll
    for (int j = 0; j < 8; j++) agg[i][j] = 0.0f;
#pragma unroll
  for (int i = 0; i < NPT; i++) {
    const int v = lane + (i << 6);
    const int beg = sm.csr_off[v], end = sm.csr_off[v + 1];
    const float dv = sm.diss[v];
    for (int e2 = beg; e2 < end; e2++) {
      const int e = sm.csr_ids[e2];
      const int r = sm.rowc[e];
      const float nrm = sm.diss[r] * sm.ewl[e] * dv;
      const float4 lo = *xvec(sm.xbuf, r, c4b);
      const float4 hi = *xvec(sm.xbuf, r, c4b + 1);
      agg[i][0] = fmaf(nrm, lo.x, agg[i][0]);
      agg[i][1] = fmaf(nrm, lo.y, agg[i][1]);
      agg[i][2] = fmaf(nrm, lo.z, agg[i][2]);
      agg[i][3] = fmaf(nrm, lo.w, agg[i][3]);
      agg[i][4] = fmaf(nrm, hi.x, agg[i][4]);
      agg[i][5] = fmaf(nrm, hi.y, agg[i][5]);
      agg[i][6] = fmaf(nrm, hi.z, agg[i][6]);
      agg[i][7] = fmaf(nrm, hi.w, agg[i][7]);
    }
  }
  __syncthreads();                 // all h reads done before in-place out

  // ---- out = relu(agg + h/deg + b); keep in acc (x1 for score gcn) ----
  {
    const float4 ba = *reinterpret_cast<const float4*>(b + fbase);
    const float4 bb = *reinterpret_cast<const float4*>(b + fbase + 4);
    const float bv[8] = {ba.x, ba.y, ba.z, ba.w, bb.x, bb.y, bb.z, bb.w};
#pragma unroll
    for (int i = 0; i < NPT; i++) {
      const int v = lane + (i << 6);
      const float invd = 1.0f / sm.degs[v];
#pragma unroll
      for (int j = 0; j < 8; j++)
        acc[i][j] = fmaxf(fmaf(acc[i][j], invd, agg[i][j] + bv[j]), 0.0f);
      *xvec(sm.xbuf, v, c4b)     = make_float4(acc[i][0], acc[i][1], acc[i][2], acc[i][3]);
      *xvec(sm.xbuf, v, c4b + 1) = make_float4(acc[i][4], acc[i][5], acc[i][6], acc[i][7]);
    }
  }
  if (tid < NN) sm.hsv[tid] = 0.0f;
  __syncthreads();

  // ---- score gcn: hs = x1 @ Wp (partials from registers) ----
  {
    const float4 wa = *reinterpret_cast<const float4*>(Wp + fbase);
    const float4 wb = *reinterpret_cast<const float4*>(Wp + fbase + 4);
    const float wv[8] = {wa.x, wa.y, wa.z, wa.w, wb.x, wb.y, wb.z, wb.w};
#pragma unroll
    for (int i = 0; i < NPT; i++) {
      float part = 0.0f;
#pragma unroll
      for (int j = 0; j < 8; j++) part = fmaf(acc[i][j], wv[j], part);
      atomicAdd(&sm.hsv[lane + (i << 6)], part);
    }
  }
  __syncthreads();
  if (tid < NN) {
    const int v = tid;
    const int beg = sm.csr_off[v], end = sm.csr_off[v + 1];
    const float dv = sm.diss[v];
    float s = 0.0f;
    for (int e2 = beg; e2 < end; e2++) {
      const int e = sm.csr_ids[e2];
      const int r = sm.rowc[e];
      s += sm.diss[r] * sm.ewl[e] * dv * sm.hsv[r];
    }
    sm.scorev[v] = s + sm.hsv[v] / sm.degs[v] + bp[0];
  }
  __syncthreads();

  // ---- exact top-k ranking (desc, ties -> lower index) ----
  if (tid < NN) {
    const float sv = sm.scorev[tid];
    int rank = 0;
    for (int u = 0; u < NN; u++) {
      const float su = sm.scorev[u];
      rank += (su > sv) || (su == sv && u < tid);
    }
    if (rank < K) { sm.perm[rank] = (short)tid; sm.vals[rank] = sv; sm.newid[tid] = (short)rank; }
    else sm.newid[tid] = -1;
  }
  __syncthreads();

  // ---- pool: x_new[i] = x[perm[i]] * tanh(vals[i]) (in-place via regs) ----
  {
    constexpr int TPR = NT / K;          // threads per dest row
    constexpr int C4  = 128 / TPR / 4;   // float4 chunks per thread
    const int drow = tid / TPR;
    const int cc   = (tid % TPR) * C4;
    const int src  = sm.perm[drow];
    const float g  = tanhf(sm.vals[drow]);
    float4 tmp[C4];
#pragma unroll
    for (int j = 0; j < C4; j++) tmp[j] = *xvec(sm.xbuf, src, cc + j);
    __syncthreads();
#pragma unroll
    for (int j = 0; j < C4; j++) {
      tmp[j].x *= g; tmp[j].y *= g; tmp[j].z *= g; tmp[j].w *= g;
      *xvec(sm.xbuf, drow, cc + j) = tmp[j];
    }
  }
  __syncthreads();

  // ---- readout: concat(max over K rows, mean over K rows) ----
  if (tid < 128) {
    float mx = -INFINITY, sv = 0.0f;
    for (int i = 0; i < K; i++) {
      const float v = sm.xbuf[xidx(i, tid)];
      mx = fmaxf(mx, v); sv += v;
    }
    leaf_out[tid] = mx;
    leaf_out[128 + tid] = sv * (1.0f / K);
  }

  // ---- remap edges into pooled id space ----
  if (do_remap) {
    for (int e = tid; e < EDGES; e += NT) {
      const unsigned short rr = sm.rowc[e];
      if (rr != SENT) {
        const short r2 = sm.newid[rr];
        const short c2 = sm.newid[sm.colc[e]];
        if (r2 < 0 || c2 < 0) sm.rowc[e] = SENT;
        else { sm.rowc[e] = (unsigned short)r2; sm.colc[e] = (unsigned short)c2; }
      }
    }
  }
  __syncthreads();
}

__global__ __launch_bounds__(NT)
void stageA_kernel(const float* __restrict__ x0,
                   const int* __restrict__ ei, const float* __restrict__ ew,
                   const float* __restrict__ W1, const float* __restrict__ b1,
                   const float* __restrict__ Wp1, const float* __restrict__ bp1,
                   const float* __restrict__ W2, const float* __restrict__ b2,
                   const float* __restrict__ Wp2, const float* __restrict__ bp2,
                   const float* __restrict__ W3, const float* __restrict__ b3,
                   const float* __restrict__ Wp3, const float* __restrict__ bp3,
                   float* __restrict__ gfeat)
{
  __shared__ SmemA sm;
  const int c = blockIdx.x;
  const int tid = threadIdx.x;
  const int* eic = ei + (size_t)c * 2 * EDGES;
  const float* ewc = ew + (size_t)c * EDGES;
  for (int e = tid; e < EDGES; e += NT) {
    sm.rowc[e] = (unsigned short)eic[e];
    sm.colc[e] = (unsigned short)eic[EDGES + e];
    sm.ewl[e]  = ewc[e];
  }
  __syncthreads();
  const float* xgc = x0 + (size_t)c * 256 * 128;
  float* leaf = gfeat + (size_t)c * 768;
  run_stage<256, 128, true >(sm, xgc,     W1, b1, Wp1, bp1, leaf + 0,   true);
  run_stage<128,  64, false>(sm, nullptr, W2, b2, Wp2, bp2, leaf + 256, true);
  run_stage< 64,  32, false>(sm, nullptr, W3, b3, Wp3, bp3, leaf + 512, false);
}

// ---------------- global stage ----------------
// blocks 0..15: parent row p (+ atomic contribution to root row, pre-zeroed)
// block 16: global degree counts
__global__ __launch_bounds__(768)
void prep_k(float* __restrict__ gfeat, const int* __restrict__ gei,
            float* __restrict__ degG) {
  const int tid = threadIdx.x;
  if (blockIdx.x == 16) {
    __shared__ int cnt[273];
    for (int i = tid; i < 273; i += 768) cnt[i] = 0;
    __syncthreads();
    for (int e = tid; e < 8192; e += 768) atomicAdd(&cnt[gei[8192 + e]], 1);
    __syncthreads();
    for (int i = tid; i < 273; i += 768) degG[i] = 1.0f + (float)cnt[i];
  } else {
    const int p = blockIdx.x;
    float s = 0.0f;
#pragma unroll 4
    for (int b2 = 0; b2 < 16; b2++) s += gfeat[(size_t)(p * 16 + b2) * 768 + tid];
    s *= (1.0f / 16.0f);
    gfeat[(size_t)(256 + p) * 768 + tid] = s;
    atomicAdd(&gfeat[(size_t)272 * 768 + tid], s * (1.0f / 16.0f));
  }
}

__global__ __launch_bounds__(256)
void gmm_k(const float* __restrict__ gfeat, const float* __restrict__ Wg,
           float* __restrict__ hG) {
  __shared__ float gf[768];
  const int v = blockIdx.x, f = threadIdx.x;
  for (int k = f; k < 768; k += 256) gf[k] = gfeat[(size_t)v * 768 + k];
  __syncthreads();
  float a = 0.0f;
#pragma unroll 4
  for (int k = 0; k < 768; k++) a = fmaf(gf[k], Wg[(size_t)k * 256 + f], a);
  hG[(size_t)v * 256 + f] = a;
}

// fused: gx row v (GCN+ReLU) -> class_embedding (v<256) -> A/B link embeddings
__global__ __launch_bounds__(256)
void gaggemb_k(const float* __restrict__ hG, const float* __restrict__ degG,
               const int* __restrict__ gei, const float* __restrict__ bg,
               const float* __restrict__ Wl1, const float* __restrict__ bl1,
               const float* __restrict__ Wl2, const float* __restrict__ bl2,
               float* __restrict__ out_ce, float* __restrict__ A,
               float* __restrict__ B) {
  __shared__ int lrows[8192];
  __shared__ int lcnt;
  __shared__ float gxr[256];
  const int v = blockIdx.x, tid = threadIdx.x;
  if (tid == 0) lcnt = 0;
  __syncthreads();
  for (int e = tid; e < 8192; e += 256)
    if (gei[8192 + e] == v) { int p = atomicAdd(&lcnt, 1); lrows[p] = gei[e]; }
  __syncthreads();
  const int n = lcnt;
  float a = 0.0f;
  for (int i = 0; i < n; i++) {
    const int r = lrows[i];
    a += rsqrtf(degG[r]) * hG[(size_t)r * 256 + tid];
  }
  float val = a * rsqrtf(degG[v]) + hG[(size_t)v * 256 + tid] / degG[v] + bg[tid];
  val = fmaxf(val, 0.0f);
  gxr[tid] = val;
  if (v < 256) out_ce[(size_t)v * 256 + tid] = val;
  __syncthreads();
  float aa = bl1[tid], bb = bl2[tid];
#pragma unroll 4
  for (int k = 0; k < 256; k++) {
    const float gv = gxr[k];
    aa = fmaf(gv, Wl1[(size_t)k * 256 + tid], aa);
    bb = fmaf(gv, Wl2[(size_t)k * 256 + tid], bb);
  }
  A[(size_t)v * 256 + tid] = aa;
  B[(size_t)v * 256 + tid] = bb;
}

__global__ void loss_k(const float* __restrict__ A, const float* __restrict__ B,
                       const int* __restrict__ gei, const int* __restrict__ nei,
                       float* __restrict__ acc) {
  const int gw = (blockIdx.x * blockDim.x + threadIdx.x) >> 6;  // 512 waves
  const int lane = threadIdx.x & 63;
  float lsum = 0.0f;
  for (int idx = gw; idx < 16384; idx += 512) {
    const bool ispos = idx < 8192;
    const int e = ispos ? idx : idx - 8192;
    const int* ia = ispos ? gei : nei;
    const int s = ia[e], t = ia[8192 + e];
    float p = 0.0f;
#pragma unroll
    for (int j = 0; j < 4; j++)
      p += A[(size_t)s * 256 + lane + 64 * j] * B[(size_t)t * 256 + lane + 64 * j];
#pragma unroll
    for (int off = 32; off; off >>= 1) p += __shfl_xor(p, off, 64);
    const float z = ispos ? -p : p;
    lsum += fmaxf(z, 0.0f) + log1pf(expf(-fabsf(z)));
  }
  if (lane == 0) atomicAdd(acc, lsum);
}

__global__ void fin_k(const float* __restrict__ acc, float* __restrict__ out) {
  out[65536] = acc[0] * (1.0f / 8192.0f);
}

extern "C" void kernel_launch(void* const* d_in, const int* in_sizes, int n_in,
                              void* d_out, int out_size, void* d_ws, size_t ws_size,
                              hipStream_t stream) {
  const float* x   = (const float*)d_in[0];
  const int*   ei  = (const int*)d_in[1];
  const float* ew  = (const float*)d_in[2];
  const int*   gei = (const int*)d_in[3];
  const int*   nei = (const int*)d_in[4];
  const float* W1  = (const float*)d_in[5];
  const float* b1  = (const float*)d_in[6];
  const float* Wp1 = (const float*)d_in[7];
  const float* bp1 = (const float*)d_in[8];
  const float* W2  = (const float*)d_in[9];
  const float* b2  = (const float*)d_in[10];
  const float* Wp2 = (const float*)d_in[11];
  const float* bp2 = (const float*)d_in[12];
  const float* W3  = (const float*)d_in[13];
  const float* b3  = (const float*)d_in[14];
  const float* Wp3 = (const float*)d_in[15];
  const float* bp3 = (const float*)d_in[16];
  const float* Wg  = (const float*)d_in[17];
  const float* bg  = (const float*)d_in[18];
  const float* Wl1 = (const float*)d_in[19];
  const float* bl1 = (const float*)d_in[20];
  const float* Wl2 = (const float*)d_in[21];
  const float* bl2 = (const float*)d_in[22];

  float* ws    = (float*)d_ws;
  float* gfeat = ws;                          // 273*768
  float* hG    = gfeat + 273 * 768;           // 273*256
  float* degG  = hG + 273 * 256;              // 288 (padded)
  float* Aemb  = degG + 288;                  // 273*256
  float* Bemb  = Aemb + 273 * 256;            // 273*256
  float* lacc  = Bemb + 273 * 256;            // 1
  float* out   = (float*)d_out;

  hipMemsetAsync(lacc, 0, sizeof(float), stream);
  hipMemsetAsync(gfeat + (size_t)272 * 768, 0, 768 * sizeof(float), stream);
  stageA_kernel<<<256, NT, 0, stream>>>(x, ei, ew, W1, b1, Wp1, bp1,
                                        W2, b2, Wp2, bp2, W3, b3, Wp3, bp3, gfeat);
  prep_k<<<17, 768, 0, stream>>>(gfeat, gei, degG);
  gmm_k<<<273, 256, 0, stream>>>(gfeat, Wg, hG);
  gaggemb_k<<<273, 256, 0, stream>>>(hG, degG, gei, bg, Wl1, bl1, Wl2, bl2,
                                     out, Aemb, Bemb);
  loss_k<<<128, 256, 0, stream>>>(Aemb, Bemb, gei, nei, lacc);
  fin_k<<<1, 1, 0, stream>>>(lacc, out);
}

// Round 3
// 223.598 us; speedup vs baseline: 1.4549x; 1.3245x over previous
//
#include <hip/hip_runtime.h>
#include <math.h>

#define NT 1024
#define EDGES 2048
#define SENT 0xFFFF

// ---------------- per-subgraph fused pipeline ----------------
// LDS: 162820 B < 163840 B.
struct SmemA {
  float xbuf[256 * 128];           // swizzled node features (128 KB)
  unsigned short rc[EDGES];        // (row<<8)|col ; SENT only in stages 2/3
  float ewl[EDGES];                // current (filtered) edge weights
  unsigned short csr_row[EDGES];   // CSR: source row per slot
  float csr_coef[EDGES];           // CSR: dis[row]*ew per slot
  float degs[256];
  float diss[256];
  int   csr_off[257];
  int   csr_cnt[256];              // also reused as top-k rank accumulator
  float hsv[256];                  // score-gcn h
  float scorev[256];
  float vals[128];                 // top-k values (rank<K<=128)
  short perm[128];
  signed char newid[256];
};

// xbuf layout: row-major 128 floats/row, float4 chunks XOR-swizzled by row&7.
__device__ __forceinline__ float4* xvec(float* xb, int row, int c4) {
  return reinterpret_cast<float4*>(xb + (row << 7) + ((c4 ^ (row & 7)) << 2));
}
__device__ __forceinline__ int xidx(int row, int col) {
  return (row << 7) + ((((col >> 2) ^ (row & 7)) << 2) | (col & 3));
}

template<int NN, int K, bool FIRST, bool REMAP>
__device__ __forceinline__ void run_stage(
    SmemA& sm,
    const float* __restrict__ xg,        // stage1: global x (else nullptr)
    const int* __restrict__ eic,         // stage1: global edge index
    const float* __restrict__ ewc,       // stage1: global edge weights
    const float* __restrict__ W,         // 128x128 row-major [k][f]
    const float* __restrict__ b,         // 128
    const float* __restrict__ Wp,        // 128
    const float* __restrict__ bp,        // 1
    float* __restrict__ leaf_out)        // 256 floats: [max(128), mean(128)]
{
  constexpr int NPT  = NN / 64;          // rows per lane (4/2/1)
  constexpr int Q    = NN / 64;          // scan items per lane
  constexpr int SEG  = NT / NN;          // rank segments per node
  constexpr int LEN  = NN / SEG;         // rank items per segment
  constexpr int LOG  = (NN == 256) ? 8 : (NN == 128 ? 7 : 6);
  const int tid  = threadIdx.x;
  const int lane = tid & 63;
  const int fbase = __builtin_amdgcn_readfirstlane((tid >> 6) << 3);
  const int c4b   = fbase >> 2;

  // ---- init ----
  if (tid < NN) { sm.degs[tid] = 1.0f; sm.csr_cnt[tid] = 0; }
  __syncthreads();

  // ---- stage x (stage1) + build deg/counts ----
  if (FIRST) {
    const float4* xg4 = reinterpret_cast<const float4*>(xg);
    for (int i = tid; i < 256 * 32; i += NT) {
      const float4 v = xg4[i];
      *xvec(sm.xbuf, i >> 5, i & 31) = v;
    }
    for (int e = tid; e < EDGES; e += NT) {
      const int row = eic[e], col = eic[EDGES + e];
      const float w = ewc[e];
      sm.rc[e]  = (unsigned short)((row << 8) | col);
      sm.ewl[e] = w;
      atomicAdd(&sm.degs[col], w);
      atomicAdd(&sm.csr_cnt[col], 1);
    }
  } else {
    for (int e = tid; e < EDGES; e += NT) {
      const unsigned short r = sm.rc[e];
      if (r != SENT) {
        atomicAdd(&sm.degs[r & 255], sm.ewl[e]);
        atomicAdd(&sm.csr_cnt[r & 255], 1);
      }
    }
  }
  __syncthreads();

  // ---- diss + one-wave shuffle scan of counts -> csr_off ----
  if (tid < NN) sm.diss[tid] = rsqrtf(sm.degs[tid]);
  if (tid < 64) {
    int c[Q], pre[Q];
    int tot = 0;
#pragma unroll
    for (int i = 0; i < Q; i++) { c[i] = sm.csr_cnt[tid * Q + i]; pre[i] = tot; tot += c[i]; }
    int inc = tot;
#pragma unroll
    for (int d = 1; d < 64; d <<= 1) {
      const int o = __shfl_up(inc, d, 64);
      if (tid >= d) inc += o;
    }
    const int base = inc - tot;
    if (tid == 0) sm.csr_off[0] = 0;
#pragma unroll
    for (int i = 0; i < Q; i++) {
      sm.csr_off[tid * Q + i + 1] = base + pre[i] + c[i];
      sm.csr_cnt[tid * Q + i] = 0;
    }
  }
  __syncthreads();

  // ---- CSR fill: slot -> (row, coef = dis[row]*ew) ----
  for (int e = tid; e < EDGES; e += NT) {
    const unsigned short r = sm.rc[e];
    if (FIRST || r != SENT) {
      const int row = r >> 8, col = r & 255;
      const int p = atomicAdd(&sm.csr_cnt[col], 1);
      const int s = sm.csr_off[col] + p;
      sm.csr_row[s]  = (unsigned short)row;
      sm.csr_coef[s] = sm.diss[row] * sm.ewl[e];
    }
  }
  __syncthreads();

  // ---- matmul: h = x @ W. Lane owns rows lane+64i; wave owns 8 cols.
  float acc[NPT][8];
#pragma unroll
  for (int i = 0; i < NPT; i++)
#pragma unroll
    for (int j = 0; j < 8; j++) acc[i][j] = 0.0f;

#pragma unroll 4
  for (int k4 = 0; k4 < 32; k4++) {
    float4 xv[NPT];
#pragma unroll
    for (int i = 0; i < NPT; i++) xv[i] = *xvec(sm.xbuf, lane + (i << 6), k4);
#pragma unroll
    for (int kk = 0; kk < 4; kk++) {
      const float* wr = W + (((k4 << 2) + kk) << 7) + fbase;
      const float4 wa = *reinterpret_cast<const float4*>(wr);
      const float4 wb = *reinterpret_cast<const float4*>(wr + 4);
      const float wv[8] = {wa.x, wa.y, wa.z, wa.w, wb.x, wb.y, wb.z, wb.w};
      const float xk[1] = {0};
      (void)xk;
#pragma unroll
      for (int i = 0; i < NPT; i++) {
        const float xs = (kk == 0) ? xv[i].x : (kk == 1) ? xv[i].y : (kk == 2) ? xv[i].z : xv[i].w;
#pragma unroll
        for (int j = 0; j < 8; j++) acc[i][j] = fmaf(xs, wv[j], acc[i][j]);
      }
    }
  }
  __syncthreads();                 // all x reads done before overwrite

  // ---- write h to xbuf ----
#pragma unroll
  for (int i = 0; i < NPT; i++) {
    const int v = lane + (i << 6);
    *xvec(sm.xbuf, v, c4b)     = make_float4(acc[i][0], acc[i][1], acc[i][2], acc[i][3]);
    *xvec(sm.xbuf, v, c4b + 1) = make_float4(acc[i][4], acc[i][5], acc[i][6], acc[i][7]);
  }
  __syncthreads();

  // ---- aggregation: agg[v] = sum coef*h[row]  (x dv at epilogue) ----
  float agg[NPT][8];
#pragma unroll
  for (int i = 0; i < NPT; i++) {
    const int v = lane + (i << 6);
    const int beg = sm.csr_off[v], end = sm.csr_off[v + 1];
#pragma unroll
    for (int j = 0; j < 8; j++) agg[i][j] = 0.0f;
    int r_nxt = 0; float c_nxt = 0.0f;
    if (beg < end) { r_nxt = sm.csr_row[beg]; c_nxt = sm.csr_coef[beg]; }
    for (int s = beg; s < end; ++s) {
      const int r = r_nxt; const float cf = c_nxt;
      if (s + 1 < end) { r_nxt = sm.csr_row[s + 1]; c_nxt = sm.csr_coef[s + 1]; }
      const float4 lo = *xvec(sm.xbuf, r, c4b);
      const float4 hi = *xvec(sm.xbuf, r, c4b + 1);
      agg[i][0] = fmaf(cf, lo.x, agg[i][0]);
      agg[i][1] = fmaf(cf, lo.y, agg[i][1]);
      agg[i][2] = fmaf(cf, lo.z, agg[i][2]);
      agg[i][3] = fmaf(cf, lo.w, agg[i][3]);
      agg[i][4] = fmaf(cf, hi.x, agg[i][4]);
      agg[i][5] = fmaf(cf, hi.y, agg[i][5]);
      agg[i][6] = fmaf(cf, hi.z, agg[i][6]);
      agg[i][7] = fmaf(cf, hi.w, agg[i][7]);
    }
  }
  if (tid < NN) sm.hsv[tid] = 0.0f;
  __syncthreads();                 // all h reads done before in-place out

  // ---- out = relu(agg*dv + h/deg + b); keep in acc; hsv partials ----
  {
    const float4 ba = *reinterpret_cast<const float4*>(b + fbase);
    const float4 bb = *reinterpret_cast<const float4*>(b + fbase + 4);
    const float bv[8] = {ba.x, ba.y, ba.z, ba.w, bb.x, bb.y, bb.z, bb.w};
#pragma unroll
    for (int i = 0; i < NPT; i++) {
      const int v = lane + (i << 6);
      const float dv = sm.diss[v];
      const float invd = 1.0f / sm.degs[v];
#pragma unroll
      for (int j = 0; j < 8; j++)
        acc[i][j] = fmaxf(fmaf(agg[i][j], dv, fmaf(acc[i][j], invd, bv[j])), 0.0f);
      *xvec(sm.xbuf, v, c4b)     = make_float4(acc[i][0], acc[i][1], acc[i][2], acc[i][3]);
      *xvec(sm.xbuf, v, c4b + 1) = make_float4(acc[i][4], acc[i][5], acc[i][6], acc[i][7]);
    }
    const float4 wa = *reinterpret_cast<const float4*>(Wp + fbase);
    const float4 wb = *reinterpret_cast<const float4*>(Wp + fbase + 4);
    const float wv[8] = {wa.x, wa.y, wa.z, wa.w, wb.x, wb.y, wb.z, wb.w};
#pragma unroll
    for (int i = 0; i < NPT; i++) {
      float part = 0.0f;
#pragma unroll
      for (int j = 0; j < 8; j++) part = fmaf(acc[i][j], wv[j], part);
      atomicAdd(&sm.hsv[lane + (i << 6)], part);
    }
  }
  __syncthreads();

  // ---- score via coef-CSR; reset rank accum ----
  if (tid < NN) {
    const int v = tid;
    const int beg = sm.csr_off[v], end = sm.csr_off[v + 1];
    float s = 0.0f;
    for (int e2 = beg; e2 < end; e2++)
      s = fmaf(sm.csr_coef[e2], sm.hsv[sm.csr_row[e2]], s);
    sm.scorev[v] = s * sm.diss[v] + sm.hsv[v] / sm.degs[v] + bp[0];
    sm.csr_cnt[v] = 0;
  }
  __syncthreads();

  // ---- parallel exact top-k rank (desc, ties -> lower index) ----
  {
    const int node = tid & (NN - 1);
    const int seg  = tid >> LOG;
    const float sv = sm.scorev[node];
    int part = 0;
    const int u0 = seg * LEN;
#pragma unroll 4
    for (int u = u0; u < u0 + LEN; u++) {
      const float su = sm.scorev[u];
      part += (su > sv) || (su == sv && u < node);
    }
    if (part) atomicAdd(&sm.csr_cnt[node], part);
  }
  __syncthreads();
  if (tid < NN) {
    const int rank = sm.csr_cnt[tid];
    if (rank < K) { sm.perm[rank] = (short)tid; sm.vals[rank] = sm.scorev[tid]; sm.newid[tid] = (signed char)rank; }
    else sm.newid[tid] = -1;
  }
  __syncthreads();

  // ---- pool: x_new[i] = x[perm[i]] * tanh(vals[i]) (in-place via regs) ----
  {
    constexpr int TPR = NT / K;          // threads per dest row
    constexpr int C4  = 32 / TPR;        // float4 chunks per thread
    const int drow = tid / TPR;
    const int cc   = (tid % TPR) * C4;
    const int src  = sm.perm[drow];
    const float g  = tanhf(sm.vals[drow]);
    float4 tmp[C4];
#pragma unroll
    for (int j = 0; j < C4; j++) tmp[j] = *xvec(sm.xbuf, src, cc + j);
    __syncthreads();
#pragma unroll
    for (int j = 0; j < C4; j++) {
      tmp[j].x *= g; tmp[j].y *= g; tmp[j].z *= g; tmp[j].w *= g;
      *xvec(sm.xbuf, drow, cc + j) = tmp[j];
    }
  }
  __syncthreads();

  // ---- readout + edge remap (independent) ----
  if (tid < 128) {
    float mx = -INFINITY, sv = 0.0f;
    for (int i = 0; i < K; i++) {
      const float v = sm.xbuf[xidx(i, tid)];
      mx = fmaxf(mx, v); sv += v;
    }
    leaf_out[tid] = mx;
    leaf_out[128 + tid] = sv * (1.0f / K);
  }
  if (REMAP) {
    for (int e = tid; e < EDGES; e += NT) {
      const unsigned short r = sm.rc[e];
      if (FIRST || r != SENT) {
        const int r2 = sm.newid[r >> 8];
        const int c2 = sm.newid[r & 255];
        sm.rc[e] = (r2 < 0 || c2 < 0) ? (unsigned short)SENT
                                      : (unsigned short)((r2 << 8) | c2);
      }
    }
  }
  __syncthreads();
}

__global__ __launch_bounds__(NT)
void stageA_kernel(const float* __restrict__ x0,
                   const int* __restrict__ ei, const float* __restrict__ ew,
                   const float* __restrict__ W1, const float* __restrict__ b1,
                   const float* __restrict__ Wp1, const float* __restrict__ bp1,
                   const float* __restrict__ W2, const float* __restrict__ b2,
                   const float* __restrict__ Wp2, const float* __restrict__ bp2,
                   const float* __restrict__ W3, const float* __restrict__ b3,
                   const float* __restrict__ Wp3, const float* __restrict__ bp3,
                   float* __restrict__ gfeat)
{
  __shared__ SmemA sm;
  const int c = blockIdx.x;
  const int* eic = ei + (size_t)c * 2 * EDGES;
  const float* ewc = ew + (size_t)c * EDGES;
  const float* xgc = x0 + (size_t)c * 256 * 128;
  float* leaf = gfeat + (size_t)c * 768;
  run_stage<256, 128, true,  true >(sm, xgc, eic, ewc, W1, b1, Wp1, bp1, leaf + 0);
  run_stage<128,  64, false, true >(sm, nullptr, nullptr, nullptr, W2, b2, Wp2, bp2, leaf + 256);
  run_stage< 64,  32, false, false>(sm, nullptr, nullptr, nullptr, W3, b3, Wp3, bp3, leaf + 512);
}

// ---------------- global stage ----------------
// blocks 0..272: hG row v (parent/root gfeat rows computed in-LDS)
// block 273: degree counts + zero the loss accumulators
__global__ __launch_bounds__(256)
void gmm_k(const float* __restrict__ gfeat, const float* __restrict__ Wg,
           float* __restrict__ hG, const int* __restrict__ gei,
           float* __restrict__ degG, float* __restrict__ lacc,
           int* __restrict__ lctr) {
  const int v = blockIdx.x, f = threadIdx.x;
  if (v == 273) {
    __shared__ int cnt[273];
    for (int i = f; i < 273; i += 256) cnt[i] = 0;
    __syncthreads();
    for (int e = f; e < 8192; e += 256) atomicAdd(&cnt[gei[8192 + e]], 1);
    __syncthreads();
    for (int i = f; i < 273; i += 256) degG[i] = 1.0f + (float)cnt[i];
    if (f == 0) { *lacc = 0.0f; *lctr = 0; }
    return;
  }
  __shared__ float gf[768];
  if (v < 256) {
    for (int k = f; k < 768; k += 256) gf[k] = gfeat[(size_t)v * 768 + k];
  } else if (v < 272) {
    const int p = v - 256;
    for (int k = f; k < 768; k += 256) {
      float s = 0.0f;
      for (int b2 = 0; b2 < 16; b2++) s += gfeat[(size_t)(p * 16 + b2) * 768 + k];
      gf[k] = s * (1.0f / 16.0f);
    }
  } else {
    for (int k = f; k < 768; k += 256) {
      float s = 0.0f;
      for (int i = 0; i < 256; i++) s += gfeat[(size_t)i * 768 + k];
      gf[k] = s * (1.0f / 256.0f);
    }
  }
  __syncthreads();
  float a = 0.0f;
#pragma unroll 8
  for (int k = 0; k < 768; k++) a = fmaf(gf[k], Wg[(size_t)k * 256 + f], a);
  hG[(size_t)v * 256 + f] = a;
}

// fused: gx row v (GCN+ReLU) -> class_embedding (v<256) -> A/B link embeddings
__global__ __launch_bounds__(256)
void gaggemb_k(const float* __restrict__ hG, const float* __restrict__ degG,
               const int* __restrict__ gei, const float* __restrict__ bg,
               const float* __restrict__ Wl1, const float* __restrict__ bl1,
               const float* __restrict__ Wl2, const float* __restrict__ bl2,
               float* __restrict__ out_ce, float* __restrict__ A,
               float* __restrict__ B) {
  __shared__ int lrows[8192];
  __shared__ int lcnt;
  __shared__ float gxr[256];
  const int v = blockIdx.x, tid = threadIdx.x;
  if (tid == 0) lcnt = 0;
  __syncthreads();
  for (int e = tid; e < 8192; e += 256)
    if (gei[8192 + e] == v) { int p = atomicAdd(&lcnt, 1); lrows[p] = gei[e]; }
  __syncthreads();
  const int n = lcnt;
  float a = 0.0f;
  for (int i = 0; i < n; i++) {
    const int r = lrows[i];
    a += rsqrtf(degG[r]) * hG[(size_t)r * 256 + tid];
  }
  float val = a * rsqrtf(degG[v]) + hG[(size_t)v * 256 + tid] / degG[v] + bg[tid];
  val = fmaxf(val, 0.0f);
  gxr[tid] = val;
  if (v < 256) out_ce[(size_t)v * 256 + tid] = val;
  __syncthreads();
  float aa = bl1[tid], bb = bl2[tid];
#pragma unroll 4
  for (int k = 0; k < 256; k++) {
    const float gv = gxr[k];
    aa = fmaf(gv, Wl1[(size_t)k * 256 + tid], aa);
    bb = fmaf(gv, Wl2[(size_t)k * 256 + tid], bb);
  }
  A[(size_t)v * 256 + tid] = aa;
  B[(size_t)v * 256 + tid] = bb;
}

// loss + finalization (last block writes out[65536])
__global__ void loss_k(const float* __restrict__ A, const float* __restrict__ B,
                       const int* __restrict__ gei, const int* __restrict__ nei,
                       float* __restrict__ acc, int* __restrict__ lctr,
                       float* __restrict__ out) {
  const int gw = (blockIdx.x * blockDim.x + threadIdx.x) >> 6;  // 512 waves
  const int lane = threadIdx.x & 63;
  float lsum = 0.0f;
  for (int idx = gw; idx < 16384; idx += 512) {
    const bool ispos = idx < 8192;
    const int e = ispos ? idx : idx - 8192;
    const int* ia = ispos ? gei : nei;
    const int s = ia[e], t = ia[8192 + e];
    float p = 0.0f;
#pragma unroll
    for (int j = 0; j < 4; j++)
      p += A[(size_t)s * 256 + lane + 64 * j] * B[(size_t)t * 256 + lane + 64 * j];
#pragma unroll
    for (int off = 32; off; off >>= 1) p += __shfl_xor(p, off, 64);
    const float z = ispos ? -p : p;
    lsum += fmaxf(z, 0.0f) + log1pf(expf(-fabsf(z)));
  }
  if (lane == 0) atomicAdd(acc, lsum);
  __syncthreads();
  if (threadIdx.x == 0) {
    __threadfence();
    const int old = atomicAdd(lctr, 1);
    if (old == (int)gridDim.x - 1) {
      const float tot = atomicAdd(acc, 0.0f);   // coherent read
      out[65536] = tot * (1.0f / 8192.0f);
    }
  }
}

extern "C" void kernel_launch(void* const* d_in, const int* in_sizes, int n_in,
                              void* d_out, int out_size, void* d_ws, size_t ws_size,
                              hipStream_t stream) {
  const float* x   = (const float*)d_in[0];
  const int*   ei  = (const int*)d_in[1];
  const float* ew  = (const float*)d_in[2];
  const int*   gei = (const int*)d_in[3];
  const int*   nei = (const int*)d_in[4];
  const float* W1  = (const float*)d_in[5];
  const float* b1  = (const float*)d_in[6];
  const float* Wp1 = (const float*)d_in[7];
  const float* bp1 = (const float*)d_in[8];
  const float* W2  = (const float*)d_in[9];
  const float* b2  = (const float*)d_in[10];
  const float* Wp2 = (const float*)d_in[11];
  const float* bp2 = (const float*)d_in[12];
  const float* W3  = (const float*)d_in[13];
  const float* b3  = (const float*)d_in[14];
  const float* Wp3 = (const float*)d_in[15];
  const float* bp3 = (const float*)d_in[16];
  const float* Wg  = (const float*)d_in[17];
  const float* bg  = (const float*)d_in[18];
  const float* Wl1 = (const float*)d_in[19];
  const float* bl1 = (const float*)d_in[20];
  const float* Wl2 = (const float*)d_in[21];
  const float* bl2 = (const float*)d_in[22];

  float* ws    = (float*)d_ws;
  float* gfeat = ws;                          // 256*768
  float* hG    = gfeat + 256 * 768;           // 273*256
  float* degG  = hG + 273 * 256;              // 288 (padded)
  float* Aemb  = degG + 288;                  // 273*256
  float* Bemb  = Aemb + 273 * 256;            // 273*256
  float* lacc  = Bemb + 273 * 256;            // 1
  int*   lctr  = (int*)(lacc + 1);            // 1
  float* out   = (float*)d_out;

  stageA_kernel<<<256, NT, 0, stream>>>(x, ei, ew, W1, b1, Wp1, bp1,
                                        W2, b2, Wp2, bp2, W3, b3, Wp3, bp3, gfeat);
  gmm_k<<<274, 256, 0, stream>>>(gfeat, Wg, hG, gei, degG, lacc, lctr);
  gaggemb_k<<<273, 256, 0, stream>>>(hG, degG, gei, bg, Wl1, bl1, Wl2, bl2,
                                     out, Aemb, Bemb);
  loss_k<<<128, 256, 0, stream>>>(Aemb, Bemb, gei, nei, lacc, lctr, out);
}

// Round 4
// 182.454 us; speedup vs baseline: 1.7830x; 1.2255x over previous
//
#include <hip/hip_runtime.h>
#include <math.h>

#define NT 1024
#define EDGES 2048
#define SENT 0xFFFF

// ---------------- per-subgraph fused pipeline ----------------
// LDS: ~159 KB < 160 KiB.
struct SmemA {
  float xbuf[256 * 128];           // swizzled node features (128 KB)
  unsigned short rc[EDGES];        // (row<<8)|col ; SENT = dropped
  float ewl[EDGES];                // current edge weights
  unsigned short csr_row[EDGES];   // CSR: source row per slot
  float csr_coef[EDGES];           // CSR: dis[row]*ew per slot (aliased: leafbuf)
  float degs[256];                 // (aliased: hGacc at end)
  float diss[256];
  int   csr_off[257];
  int   csr_cnt[256];              // counts / scan input / rank accumulator
  float hsv[256];                  // score-gcn h
  float scorev[256];
  float vals[128];
  short perm[128];
  signed char newid[256];
};

// xbuf layout: row-major 128 floats/row, float4 chunks XOR-swizzled by row&7.
__device__ __forceinline__ float4* xvec(float* xb, int row, int c4) {
  return reinterpret_cast<float4*>(xb + (row << 7) + ((c4 ^ (row & 7)) << 2));
}
__device__ __forceinline__ int xidx(int row, int col) {
  return (row << 7) + ((((col >> 2) ^ (row & 7)) << 2) | (col & 3));
}

template<int NN, int K, bool FIRST, bool REMAP>
__device__ __forceinline__ void run_stage(
    SmemA& sm,
    const float* __restrict__ xg,        // stage1: global x (else nullptr)
    const int* __restrict__ eic,         // stage1: global edge index
    const float* __restrict__ ewc,       // stage1: global edge weights
    const float* __restrict__ W,         // 128x128 row-major [k][f]
    const float* __restrict__ b,         // 128
    const float* __restrict__ Wp,        // 128
    const float* __restrict__ bp,        // 1
    float* __restrict__ leaf_out,        // 256 floats: [max(128), mean(128)]
    float& lmax, float& lmean)           // register copies (tid<128)
{
  constexpr int NPT  = NN / 64;          // rows per lane (4/2/1)
  constexpr int Q    = NN / 64;          // scan items per lane
  constexpr int SEG  = NT / NN;          // rank segments per node
  constexpr int LEN  = NN / SEG;         // rank items per segment
  constexpr int LOG  = (NN == 256) ? 8 : (NN == 128 ? 7 : 6);
  const int tid  = threadIdx.x;
  const int lane = tid & 63;
  const int fbase = __builtin_amdgcn_readfirstlane((tid >> 6) << 3);
  const int c4b   = fbase >> 2;

  // ---- stage1 only: stage x + edges, build deg/counts ----
  // (stages 2/3: deg/counts were accumulated during the previous remap)
  if (FIRST) {
    if (tid < NN) { sm.degs[tid] = 1.0f; sm.csr_cnt[tid] = 0; }
    __syncthreads();
    const float4* xg4 = reinterpret_cast<const float4*>(xg);
    for (int i = tid; i < 256 * 32; i += NT) {
      const float4 v = xg4[i];
      *xvec(sm.xbuf, i >> 5, i & 31) = v;
    }
    for (int e = tid; e < EDGES; e += NT) {
      const int row = eic[e], col = eic[EDGES + e];
      const float w = ewc[e];
      sm.rc[e]  = (unsigned short)((row << 8) | col);
      sm.ewl[e] = w;
      atomicAdd(&sm.degs[col], w);
      atomicAdd(&sm.csr_cnt[col], 1);
    }
    __syncthreads();
  }

  // ---- diss + one-wave shuffle scan of counts -> csr_off ----
  if (tid < NN) sm.diss[tid] = rsqrtf(sm.degs[tid]);
  if (tid < 64) {
    int c[Q], pre[Q];
    int tot = 0;
#pragma unroll
    for (int i = 0; i < Q; i++) { c[i] = sm.csr_cnt[tid * Q + i]; pre[i] = tot; tot += c[i]; }
    int inc = tot;
#pragma unroll
    for (int d = 1; d < 64; d <<= 1) {
      const int o = __shfl_up(inc, d, 64);
      if (tid >= d) inc += o;
    }
    const int base = inc - tot;
    if (tid == 0) sm.csr_off[0] = 0;
#pragma unroll
    for (int i = 0; i < Q; i++) {
      sm.csr_off[tid * Q + i + 1] = base + pre[i] + c[i];
      sm.csr_cnt[tid * Q + i] = 0;
    }
  }
  __syncthreads();

  // ---- CSR fill: slot -> (row, coef = dis[row]*ew) ----
  for (int e = tid; e < EDGES; e += NT) {
    const unsigned short r = sm.rc[e];
    if (FIRST || r != SENT) {
      const int row = r >> 8, col = r & 255;
      const int p = atomicAdd(&sm.csr_cnt[col], 1);
      const int s = sm.csr_off[col] + p;
      sm.csr_row[s]  = (unsigned short)row;
      sm.csr_coef[s] = sm.diss[row] * sm.ewl[e];
    }
  }
  __syncthreads();

  // ---- matmul: h = x @ W. Lane owns rows lane+64i; wave owns 8 cols. ----
  float acc[NPT][8];
#pragma unroll
  for (int i = 0; i < NPT; i++)
#pragma unroll
    for (int j = 0; j < 8; j++) acc[i][j] = 0.0f;

#pragma unroll 4
  for (int k4 = 0; k4 < 32; k4++) {
    float4 xv[NPT];
#pragma unroll
    for (int i = 0; i < NPT; i++) xv[i] = *xvec(sm.xbuf, lane + (i << 6), k4);
#pragma unroll
    for (int kk = 0; kk < 4; kk++) {
      const float* wr = W + (((k4 << 2) + kk) << 7) + fbase;
      const float4 wa = *reinterpret_cast<const float4*>(wr);
      const float4 wb = *reinterpret_cast<const float4*>(wr + 4);
      const float wv[8] = {wa.x, wa.y, wa.z, wa.w, wb.x, wb.y, wb.z, wb.w};
#pragma unroll
      for (int i = 0; i < NPT; i++) {
        const float xs = (kk == 0) ? xv[i].x : (kk == 1) ? xv[i].y : (kk == 2) ? xv[i].z : xv[i].w;
#pragma unroll
        for (int j = 0; j < 8; j++) acc[i][j] = fmaf(xs, wv[j], acc[i][j]);
      }
    }
  }
  __syncthreads();                 // all x reads done before overwrite

  // ---- write h to xbuf ----
#pragma unroll
  for (int i = 0; i < NPT; i++) {
    const int v = lane + (i << 6);
    *xvec(sm.xbuf, v, c4b)     = make_float4(acc[i][0], acc[i][1], acc[i][2], acc[i][3]);
    *xvec(sm.xbuf, v, c4b + 1) = make_float4(acc[i][4], acc[i][5], acc[i][6], acc[i][7]);
  }
  __syncthreads();

  // ---- aggregation: agg[v] = sum coef*h[row]  (x dv at epilogue) ----
  float agg[NPT][8];
#pragma unroll
  for (int i = 0; i < NPT; i++) {
    const int v = lane + (i << 6);
    const int beg = sm.csr_off[v], end = sm.csr_off[v + 1];
#pragma unroll
    for (int j = 0; j < 8; j++) agg[i][j] = 0.0f;
    int r_nxt = 0; float c_nxt = 0.0f;
    if (beg < end) { r_nxt = sm.csr_row[beg]; c_nxt = sm.csr_coef[beg]; }
    for (int s = beg; s < end; ++s) {
      const int r = r_nxt; const float cf = c_nxt;
      if (s + 1 < end) { r_nxt = sm.csr_row[s + 1]; c_nxt = sm.csr_coef[s + 1]; }
      const float4 lo = *xvec(sm.xbuf, r, c4b);
      const float4 hi = *xvec(sm.xbuf, r, c4b + 1);
      agg[i][0] = fmaf(cf, lo.x, agg[i][0]);
      agg[i][1] = fmaf(cf, lo.y, agg[i][1]);
      agg[i][2] = fmaf(cf, lo.z, agg[i][2]);
      agg[i][3] = fmaf(cf, lo.w, agg[i][3]);
      agg[i][4] = fmaf(cf, hi.x, agg[i][4]);
      agg[i][5] = fmaf(cf, hi.y, agg[i][5]);
      agg[i][6] = fmaf(cf, hi.z, agg[i][6]);
      agg[i][7] = fmaf(cf, hi.w, agg[i][7]);
    }
  }
  if (tid < NN) sm.hsv[tid] = 0.0f;
  __syncthreads();                 // all h reads done before in-place out

  // ---- out = relu(agg*dv + h/deg + b); keep in acc; hsv partials ----
  {
    const float4 ba = *reinterpret_cast<const float4*>(b + fbase);
    const float4 bb = *reinterpret_cast<const float4*>(b + fbase + 4);
    const float bv[8] = {ba.x, ba.y, ba.z, ba.w, bb.x, bb.y, bb.z, bb.w};
#pragma unroll
    for (int i = 0; i < NPT; i++) {
      const int v = lane + (i << 6);
      const float dv = sm.diss[v];
      const float invd = 1.0f / sm.degs[v];
#pragma unroll
      for (int j = 0; j < 8; j++)
        acc[i][j] = fmaxf(fmaf(agg[i][j], dv, fmaf(acc[i][j], invd, bv[j])), 0.0f);
      *xvec(sm.xbuf, v, c4b)     = make_float4(acc[i][0], acc[i][1], acc[i][2], acc[i][3]);
      *xvec(sm.xbuf, v, c4b + 1) = make_float4(acc[i][4], acc[i][5], acc[i][6], acc[i][7]);
    }
    const float4 wa = *reinterpret_cast<const float4*>(Wp + fbase);
    const float4 wb = *reinterpret_cast<const float4*>(Wp + fbase + 4);
    const float wv[8] = {wa.x, wa.y, wa.z, wa.w, wb.x, wb.y, wb.z, wb.w};
#pragma unroll
    for (int i = 0; i < NPT; i++) {
      float part = 0.0f;
#pragma unroll
      for (int j = 0; j < 8; j++) part = fmaf(acc[i][j], wv[j], part);
      atomicAdd(&sm.hsv[lane + (i << 6)], part);
    }
  }
  __syncthreads();

  // ---- score via coef-CSR; reset rank accumulator ----
  if (tid < NN) {
    const int v = tid;
    const int beg = sm.csr_off[v], end = sm.csr_off[v + 1];
    float s = 0.0f;
    for (int e2 = beg; e2 < end; e2++)
      s = fmaf(sm.csr_coef[e2], sm.hsv[sm.csr_row[e2]], s);
    sm.scorev[v] = s * sm.diss[v] + sm.hsv[v] / sm.degs[v] + bp[0];
    sm.csr_cnt[v] = 0;
  }
  __syncthreads();

  // ---- parallel exact top-k rank (desc, ties -> lower index) ----
  {
    const int node = tid & (NN - 1);
    const int seg  = tid >> LOG;
    const float sv = sm.scorev[node];
    int part = 0;
    const int u0 = seg * LEN;
#pragma unroll 4
    for (int u = u0; u < u0 + LEN; u++) {
      const float su = sm.scorev[u];
      part += (su > sv) || (su == sv && u < node);
    }
    if (part) atomicAdd(&sm.csr_cnt[node], part);
  }
  __syncthreads();
  if (tid < NN) {
    const int rank = sm.csr_cnt[tid];
    if (rank < K) { sm.perm[rank] = (short)tid; sm.vals[rank] = sm.scorev[tid]; sm.newid[tid] = (signed char)rank; }
    else sm.newid[tid] = -1;
    if (tid < K) { sm.degs[tid] = 1.0f; sm.csr_cnt[tid] = 0; }   // init next stage
  }
  __syncthreads();

  // ---- pool: x_new[i] = x[perm[i]] * tanh(vals[i]) (in-place via regs) ----
  {
    constexpr int TPR = NT / K;          // threads per dest row
    constexpr int C4  = 32 / TPR;        // float4 chunks per thread
    const int drow = tid / TPR;
    const int cc   = (tid % TPR) * C4;
    const int src  = sm.perm[drow];
    const float g  = tanhf(sm.vals[drow]);
    float4 tmp[C4];
#pragma unroll
    for (int j = 0; j < C4; j++) tmp[j] = *xvec(sm.xbuf, src, cc + j);
    __syncthreads();
#pragma unroll
    for (int j = 0; j < C4; j++) {
      tmp[j].x *= g; tmp[j].y *= g; tmp[j].z *= g; tmp[j].w *= g;
      *xvec(sm.xbuf, drow, cc + j) = tmp[j];
    }
  }
  __syncthreads();

  // ---- readout + edge remap (+ next-stage deg/count accumulation) ----
  if (tid < 128) {
    float mx = -INFINITY, sv = 0.0f;
    for (int i = 0; i < K; i++) {
      const float v = sm.xbuf[xidx(i, tid)];
      mx = fmaxf(mx, v); sv += v;
    }
    lmax = mx;
    lmean = sv * (1.0f / K);
    leaf_out[tid] = mx;
    leaf_out[128 + tid] = lmean;
  }
  if (REMAP) {
    for (int e = tid; e < EDGES; e += NT) {
      const unsigned short r = sm.rc[e];
      if (FIRST || r != SENT) {
        const int r2 = sm.newid[r >> 8];
        const int c2 = sm.newid[r & 255];
        if (r2 < 0 || c2 < 0) sm.rc[e] = SENT;
        else {
          sm.rc[e] = (unsigned short)((r2 << 8) | c2);
          atomicAdd(&sm.degs[c2], sm.ewl[e]);
          atomicAdd(&sm.csr_cnt[c2], 1);
        }
      }
    }
  }
  __syncthreads();
}

__global__ __launch_bounds__(NT)
void stageA_kernel(const float* __restrict__ x0,
                   const int* __restrict__ ei, const float* __restrict__ ew,
                   const float* __restrict__ W1, const float* __restrict__ b1,
                   const float* __restrict__ Wp1, const float* __restrict__ bp1,
                   const float* __restrict__ W2, const float* __restrict__ b2,
                   const float* __restrict__ Wp2, const float* __restrict__ bp2,
                   const float* __restrict__ W3, const float* __restrict__ b3,
                   const float* __restrict__ Wp3, const float* __restrict__ bp3,
                   const float* __restrict__ Wg,
                   float* __restrict__ gfeat, float* __restrict__ hG)
{
  __shared__ SmemA sm;
  const int c = blockIdx.x;
  const int tid = threadIdx.x;
  if (c == 0 && tid < 256) hG[(size_t)272 * 256 + tid] = 0.0f;   // root hG accum
  const int* eic = ei + (size_t)c * 2 * EDGES;
  const float* ewc = ew + (size_t)c * EDGES;
  const float* xgc = x0 + (size_t)c * 256 * 128;
  float* leaf = gfeat + (size_t)c * 768;
  float l0 = 0.f, l1 = 0.f, l2 = 0.f, l3 = 0.f, l4 = 0.f, l5 = 0.f;
  run_stage<256, 128, true,  true >(sm, xgc, eic, ewc, W1, b1, Wp1, bp1, leaf + 0,   l0, l1);
  run_stage<128,  64, false, true >(sm, nullptr, nullptr, nullptr, W2, b2, Wp2, bp2, leaf + 256, l2, l3);
  run_stage< 64,  32, false, false>(sm, nullptr, nullptr, nullptr, W3, b3, Wp3, bp3, leaf + 512, l4, l5);

  // ---- fused leaf hG row: hG[c] = leaf(768) @ Wg(768x256) ----
  float* leafbuf = sm.csr_coef;   // dead after stage-3 score
  float* hGacc   = sm.degs;       // dead after stage-3
  if (tid < 256) {
    if (tid < 128) {
      leafbuf[tid]       = l0; leafbuf[128 + tid] = l1;
      leafbuf[256 + tid] = l2; leafbuf[384 + tid] = l3;
      leafbuf[512 + tid] = l4; leafbuf[640 + tid] = l5;
    }
    hGacc[tid] = 0.0f;
  }
  __syncthreads();
  {
    const int f = tid & 255, q = tid >> 8;       // 4 k-quarters x 192
    const float* wgq = Wg + (size_t)(q * 192) * 256 + f;
    const float* lb  = leafbuf + q * 192;
    float p0 = 0.f, p1 = 0.f, p2 = 0.f, p3 = 0.f;
    for (int i = 0; i < 192; i += 4) {
      p0 = fmaf(lb[i],     wgq[(size_t)i * 256],      p0);
      p1 = fmaf(lb[i + 1], wgq[(size_t)(i + 1) * 256], p1);
      p2 = fmaf(lb[i + 2], wgq[(size_t)(i + 2) * 256], p2);
      p3 = fmaf(lb[i + 3], wgq[(size_t)(i + 3) * 256], p3);
    }
    atomicAdd(&hGacc[f], (p0 + p1) + (p2 + p3));
  }
  __syncthreads();
  if (tid < 256) hG[(size_t)c * 256 + tid] = hGacc[tid];
}

// ---------------- global stage ----------------
// blocks 0..15: parent p -> hG[256+p] + (1/16) into hG[272]
// block 16: degG + zero loss accumulators
__global__ __launch_bounds__(NT)
void prep_k(const float* __restrict__ gfeat, const float* __restrict__ Wg,
            float* __restrict__ hG, const int* __restrict__ gei,
            float* __restrict__ degG, float* __restrict__ lacc,
            int* __restrict__ lctr) {
  const int tid = threadIdx.x;
  if (blockIdx.x == 16) {
    __shared__ int cnt[273];
    for (int i = tid; i < 273; i += NT) cnt[i] = 0;
    __syncthreads();
    for (int e = tid; e < 8192; e += NT) atomicAdd(&cnt[gei[8192 + e]], 1);
    __syncthreads();
    for (int i = tid; i < 273; i += NT) degG[i] = 1.0f + (float)cnt[i];
    if (tid == 0) { *lacc = 0.0f; *lctr = 0; }
    return;
  }
  const int p = blockIdx.x;
  __shared__ float prow[768];
  __shared__ float hGacc[256];
  for (int k = tid; k < 768; k += NT) {
    float s0 = 0.f, s1 = 0.f;
#pragma unroll
    for (int b2 = 0; b2 < 16; b2 += 2) {
      s0 += gfeat[(size_t)(p * 16 + b2) * 768 + k];
      s1 += gfeat[(size_t)(p * 16 + b2 + 1) * 768 + k];
    }
    prow[k] = (s0 + s1) * (1.0f / 16.0f);
  }
  if (tid < 256) hGacc[tid] = 0.0f;
  __syncthreads();
  {
    const int f = tid & 255, q = tid >> 8;
    const float* wgq = Wg + (size_t)(q * 192) * 256 + f;
    const float* lb  = prow + q * 192;
    float p0 = 0.f, p1 = 0.f, p2 = 0.f, p3 = 0.f;
    for (int i = 0; i < 192; i += 4) {
      p0 = fmaf(lb[i],     wgq[(size_t)i * 256],      p0);
      p1 = fmaf(lb[i + 1], wgq[(size_t)(i + 1) * 256], p1);
      p2 = fmaf(lb[i + 2], wgq[(size_t)(i + 2) * 256], p2);
      p3 = fmaf(lb[i + 3], wgq[(size_t)(i + 3) * 256], p3);
    }
    atomicAdd(&hGacc[f], (p0 + p1) + (p2 + p3));
  }
  __syncthreads();
  if (tid < 256) {
    const float hv = hGacc[tid];
    hG[(size_t)(256 + p) * 256 + tid] = hv;
    atomicAdd(&hG[(size_t)272 * 256 + tid], hv * (1.0f / 16.0f));
  }
}

// fused: gx row v (GCN+ReLU) -> class_embedding (v<256) -> A/B link embeddings
__global__ __launch_bounds__(256)
void gaggemb_k(const float* __restrict__ hG, const float* __restrict__ degG,
               const int* __restrict__ gei, const float* __restrict__ bg,
               const float* __restrict__ Wl1, const float* __restrict__ bl1,
               const float* __restrict__ Wl2, const float* __restrict__ bl2,
               float* __restrict__ out_ce, float* __restrict__ A,
               float* __restrict__ B) {
  __shared__ int   lrows[512];
  __shared__ float lcoef[512];
  __shared__ float gxr[256];
  __shared__ int   lcnt;
  const int v = blockIdx.x, tid = threadIdx.x;
  if (tid == 0) lcnt = 0;
  __syncthreads();
  for (int e = tid; e < 8192; e += 256)
    if (gei[8192 + e] == v) {
      const int p = atomicAdd(&lcnt, 1);
      if (p < 512) lrows[p] = gei[e];
    }
  __syncthreads();
  const int n = min(lcnt, 512);
  for (int i = tid; i < n; i += 256) lcoef[i] = rsqrtf(degG[lrows[i]]);
  __syncthreads();
  float a0 = 0.f, a1 = 0.f, a2 = 0.f, a3 = 0.f;
  int i = 0;
  for (; i + 4 <= n; i += 4) {
    a0 = fmaf(lcoef[i],     hG[(size_t)lrows[i]     * 256 + tid], a0);
    a1 = fmaf(lcoef[i + 1], hG[(size_t)lrows[i + 1] * 256 + tid], a1);
    a2 = fmaf(lcoef[i + 2], hG[(size_t)lrows[i + 2] * 256 + tid], a2);
    a3 = fmaf(lcoef[i + 3], hG[(size_t)lrows[i + 3] * 256 + tid], a3);
  }
  for (; i < n; i++) a0 = fmaf(lcoef[i], hG[(size_t)lrows[i] * 256 + tid], a0);
  const float dg = degG[v];
  float val = ((a0 + a1) + (a2 + a3)) * rsqrtf(dg)
            + hG[(size_t)v * 256 + tid] / dg + bg[tid];
  val = fmaxf(val, 0.0f);
  gxr[tid] = val;
  if (v < 256) out_ce[(size_t)v * 256 + tid] = val;
  __syncthreads();
  float aa0 = bl1[tid], aa1 = 0.f, aa2 = 0.f, aa3 = 0.f;
  float bb0 = bl2[tid], bb1 = 0.f, bb2 = 0.f, bb3 = 0.f;
  for (int k = 0; k < 256; k += 4) {
    const float g0 = gxr[k], g1 = gxr[k + 1], g2 = gxr[k + 2], g3 = gxr[k + 3];
    aa0 = fmaf(g0, Wl1[(size_t)k * 256 + tid],       aa0);
    aa1 = fmaf(g1, Wl1[(size_t)(k + 1) * 256 + tid], aa1);
    aa2 = fmaf(g2, Wl1[(size_t)(k + 2) * 256 + tid], aa2);
    aa3 = fmaf(g3, Wl1[(size_t)(k + 3) * 256 + tid], aa3);
    bb0 = fmaf(g0, Wl2[(size_t)k * 256 + tid],       bb0);
    bb1 = fmaf(g1, Wl2[(size_t)(k + 1) * 256 + tid], bb1);
    bb2 = fmaf(g2, Wl2[(size_t)(k + 2) * 256 + tid], bb2);
    bb3 = fmaf(g3, Wl2[(size_t)(k + 3) * 256 + tid], bb3);
  }
  A[(size_t)v * 256 + tid] = (aa0 + aa1) + (aa2 + aa3);
  B[(size_t)v * 256 + tid] = (bb0 + bb1) + (bb2 + bb3);
}

// loss + finalization (last block writes out[65536])
__global__ __launch_bounds__(256)
void loss_k(const float* __restrict__ A, const float* __restrict__ B,
            const int* __restrict__ gei, const int* __restrict__ nei,
            float* __restrict__ acc, int* __restrict__ lctr,
            float* __restrict__ out) {
  const int gw = (blockIdx.x * blockDim.x + threadIdx.x) >> 6;  // 512 waves
  const int lane = threadIdx.x & 63;
  float lsum = 0.0f;
  for (int idx = gw; idx < 16384; idx += 512) {
    const bool ispos = idx < 8192;
    const int e = ispos ? idx : idx - 8192;
    const int* ia = ispos ? gei : nei;
    const int s = ia[e], t = ia[8192 + e];
    float p = 0.0f;
#pragma unroll
    for (int j = 0; j < 4; j++)
      p += A[(size_t)s * 256 + lane + 64 * j] * B[(size_t)t * 256 + lane + 64 * j];
#pragma unroll
    for (int off = 32; off; off >>= 1) p += __shfl_xor(p, off, 64);
    const float z = ispos ? -p : p;
    lsum += fmaxf(z, 0.0f) + log1pf(expf(-fabsf(z)));
  }
  if (lane == 0) atomicAdd(acc, lsum);
  __syncthreads();
  if (threadIdx.x == 0) {
    __threadfence();
    const int old = atomicAdd(lctr, 1);
    if (old == (int)gridDim.x - 1) {
      const float tot = atomicAdd(acc, 0.0f);   // coherent read
      out[65536] = tot * (1.0f / 8192.0f);
    }
  }
}

extern "C" void kernel_launch(void* const* d_in, const int* in_sizes, int n_in,
                              void* d_out, int out_size, void* d_ws, size_t ws_size,
                              hipStream_t stream) {
  const float* x   = (const float*)d_in[0];
  const int*   ei  = (const int*)d_in[1];
  const float* ew  = (const float*)d_in[2];
  const int*   gei = (const int*)d_in[3];
  const int*   nei = (const int*)d_in[4];
  const float* W1  = (const float*)d_in[5];
  const float* b1  = (const float*)d_in[6];
  const float* Wp1 = (const float*)d_in[7];
  const float* bp1 = (const float*)d_in[8];
  const float* W2  = (const float*)d_in[9];
  const float* b2  = (const float*)d_in[10];
  const float* Wp2 = (const float*)d_in[11];
  const float* bp2 = (const float*)d_in[12];
  const float* W3  = (const float*)d_in[13];
  const float* b3  = (const float*)d_in[14];
  const float* Wp3 = (const float*)d_in[15];
  const float* bp3 = (const float*)d_in[16];
  const float* Wg  = (const float*)d_in[17];
  const float* bg  = (const float*)d_in[18];
  const float* Wl1 = (const float*)d_in[19];
  const float* bl1 = (const float*)d_in[20];
  const float* Wl2 = (const float*)d_in[21];
  const float* bl2 = (const float*)d_in[22];

  float* ws    = (float*)d_ws;
  float* gfeat = ws;                          // 256*768 (leaf rows only)
  float* hG    = gfeat + 256 * 768;           // 273*256
  float* degG  = hG + 273 * 256;              // 288 (padded)
  float* Aemb  = degG + 288;                  // 273*256
  float* Bemb  = Aemb + 273 * 256;            // 273*256
  float* lacc  = Bemb + 273 * 256;            // 1
  int*   lctr  = (int*)(lacc + 1);            // 1
  float* out   = (float*)d_out;

  stageA_kernel<<<256, NT, 0, stream>>>(x, ei, ew, W1, b1, Wp1, bp1,
                                        W2, b2, Wp2, bp2, W3, b3, Wp3, bp3,
                                        Wg, gfeat, hG);
  prep_k<<<17, NT, 0, stream>>>(gfeat, Wg, hG, gei, degG, lacc, lctr);
  gaggemb_k<<<273, 256, 0, stream>>>(hG, degG, gei, bg, Wl1, bl1, Wl2, bl2,
                                     out, Aemb, Bemb);
  loss_k<<<128, 256, 0, stream>>>(Aemb, Bemb, gei, nei, lacc, lctr, out);
}